// Round 20
// baseline (1487.176 us; speedup 1.0000x reference)
//
#include <hip/hip_runtime.h>

// BinaryCorrelationMatcher: B=4, H=480, W=640, TEMPLATE=21 (pad 10), SEARCH=9.
//
// VERIFIED reference model (R14): corr = flat forward-raster sequential f32
// sum over 441 taps of the FMA-contracted agreement:
//   agr = fma(p1, s2, fl( fl(1-p1) * fl(1-s2) ));  s = fl(s + agr)
// s2 = shifted p2 (0 outside image); OOB taps exact +0 no-ops.
// Winner = (max f32, min k) = lax.scan strict-> first-wins.
//
// Pass 1 (R20 = R18 base + 8-row phase2): R19's tree-sum/register-array
// variant REGRESSED (scratch spills: WRITE_SIZE 14.6->23 MB) — reverted.
// R18 audit: LDS pipe is the binding resource; phase2's 27 b32 reads/thread
// x 4 waves (108 wave-reads, ~557 cyc/block-offset) carry 3.7x redundancy.
// R20: phase2 uses 128 threads x 8 output rows (21 init + 7x2 slide reads
// = 35/thread, 70 wave-reads) — amortizes the 21-row window init over 2x
// the outputs. Phase1 unchanged: q-taps global->28 regs, p-taps circular
// 28-reg window (1 LDS refill/dx), rowsum slabs ping-ponged -> ONE barrier
// per offset. LDS 34.9K -> 4 blocks/CU; launch_bounds(256,4) caps VGPR=128.
// MARGIN 0.002 (R17): pass1-vs-ref sigma ~1.4e-4; budget 1e-3 = ~7 sigma.
// Flagged: normal -> front worklist (<=4 cands); deep (top-4 within margin)
// -> back worklist (361-replay). Overflow -> sentinel in flow slots.
//
// Pass 2: normal 16/wave (lane quad, shfl_xor); deep wave-per-entry; then
// overflow-gated sentinel scan (normally a uniform early-out).
//
// Confidence: clip(((boxsum(q)+Nvalid)/2)/441, 0, 1), f32 (threshold 0.02).

#define HH 480
#define WW 640
#define TH 32
#define TW 32
#define QROWS 52   // TH+20
#define PROWS 70   // TH+38
#define PCOLS 70   // TW+38
#define PSTR  71
#define RSTR  36   // f32 rowsum slab stride (mult of 4 -> float4 writes)
#define MARGIN 0.002f
#define NPIX (4 * HH * WW)

// Bit-exact replica: forward-raster sequential f32 sum of FMA-contracted taps.
__device__ __forceinline__ float replay_corr(const float* __restrict__ p1b,
                                             const float* __restrict__ p2b,
                                             int y, int x, int k) {
  int dy = k / 19 - 9, dx = k % 19 - 9;
  float s = 0.f;
  for (int u = 0; u < 21; ++u) {
    int yy = y - 10 + u;
    if (yy < 0 || yy >= HH) continue;  // +0 taps: exact no-ops
    int y2 = yy + dy;
    bool yok = (y2 >= 0 && y2 < HH);
    const float* r1 = p1b + yy * WW;
    const float* r2 = p2b + y2 * WW;
#pragma unroll
    for (int v = 0; v < 21; ++v) {
      int xx = x - 10 + v;
      if (xx < 0 || xx >= WW) continue;  // +0 tap: exact no-op
      float p = r1[xx];
      int x2 = xx + dx;
      float s2 = (yok && x2 >= 0 && x2 < WW) ? r2[x2] : 0.f;
      float t2 = __fmul_rn(__fsub_rn(1.f, p), __fsub_rn(1.f, s2));
      float agr = __fmaf_rn(p, s2, t2);
      s = __fadd_rn(s, agr);
    }
  }
  return s;
}

__global__ __launch_bounds__(256, 4)
void bcm_pass1(const float* __restrict__ p1, const float* __restrict__ p2,
               float* __restrict__ out, unsigned* __restrict__ wl,
               unsigned capE) {
  __shared__ float ps[PROWS * PSTR];
  __shared__ __align__(16) float rsb0[QROWS * RSTR];
  __shared__ __align__(16) float rsb1[QROWS * RSTR];

  const int tid = threadIdx.x;
  const int b  = blockIdx.z;
  const int y0 = blockIdx.y * TH;
  const int x0 = blockIdx.x * TW;
  const float* p1b = p1 + b * HH * WW;
  const float* p2b = p2 + b * HH * WW;

  // stage p2 tile (halo 19) into LDS
  for (int i = tid; i < PROWS * PCOLS; i += 256) {
    int rr = i / PCOLS, cc = i - rr * PCOLS;
    int Y = y0 - 19 + rr, X = x0 - 19 + cc;
    float v = 0.f;
    if (Y >= 0 && Y < HH && X >= 0 && X < WW) v = p2b[Y * WW + X];
    ps[rr * PSTR + cc] = v;
  }

  // phase2 mapping (R20): 128 threads, 8 output rows each
  const int col = tid & 31;
  const int r0  = (tid >> 5) * 8;         // valid for tid < 128
  const bool active2 = (tid < 128);
  // phase1 mapping: 208 threads, one rowsum row x 8-col strip
  const int prow_ = tid >> 2;
  const int c0    = (tid & 3) * 8;
  const bool active1 = (prow_ < QROWS);

  // q taps straight from global into registers (28 = 21 + 7 for 8 cols)
  float qreg[28];
  if (active1) {
    int Y = y0 - 10 + prow_;
    bool yok = (Y >= 0 && Y < HH);
    const float* qrow = p1b + Y * WW;
#pragma unroll
    for (int t = 0; t < 28; ++t) {
      int X = x0 - 10 + c0 + t;
      float v = 0.f;
      if (yok && X >= 0 && X < WW) v = 2.f * qrow[X] - 1.f;
      qreg[t] = v;
    }
  }
  __syncthreads();

  // top-4 candidates per output pixel (sorted descending)
  float bv[8][4];
  int   bk[8][4];
#pragma unroll
  for (int j = 0; j < 8; ++j)
#pragma unroll
    for (int t = 0; t < 4; ++t) { bv[j][t] = -1e30f; bk[j][t] = 0; }

  float preg[28];  // circular window of p taps
  int k = 0;
  for (int dy = -9; dy <= 9; ++dy) {
    const float* prowp = active1 ? &ps[(prow_ + dy + 9) * PSTR + c0] : ps;
    if (active1) {
#pragma unroll
      for (int t = 0; t < 28; ++t) preg[t] = prowp[t];
    }
#pragma unroll
    for (int dxi = 0; dxi < 19; ++dxi, ++k) {
      float* slab = (k & 1) ? rsb1 : rsb0;
      if (active1) {
        float s = 0.f;
#pragma unroll
        for (int t = 0; t < 21; ++t) s += qreg[t] * preg[(dxi + t) % 28];
        float rs[8];
        rs[0] = s;
#pragma unroll
        for (int j = 1; j < 8; ++j) {
          s += qreg[j + 20] * preg[(dxi + j + 20) % 28]
             - qreg[j - 1] * preg[(dxi + j - 1) % 28];
          rs[j] = s;
        }
        float4* w = (float4*)&slab[prow_ * RSTR + c0];
        w[0] = make_float4(rs[0], rs[1], rs[2], rs[3]);
        w[1] = make_float4(rs[4], rs[5], rs[6], rs[7]);
        if (dxi < 18) preg[dxi % 28] = prowp[dxi + 28];  // next tap
      }
      __syncthreads();  // single barrier per offset (ping-pong slabs)
      if (active2) {
        float s = 0.f;
#pragma unroll
        for (int u = 0; u < 21; ++u) s += slab[(r0 + u) * RSTR + col];
#pragma unroll
        for (int j = 0; j < 8; ++j) {
          if (j > 0) s += slab[(r0 + 20 + j) * RSTR + col]
                        - slab[(r0 + j - 1) * RSTR + col];
          float cv = s;
          if (cv > bv[j][3]) {
            int ck = k;
#pragma unroll
            for (int t = 0; t < 4; ++t) {   // sorted-insert; strict >
              if (cv > bv[j][t]) {
                float tv = bv[j][t]; int tk = bk[j][t];
                bv[j][t] = cv; bk[j][t] = ck;
                cv = tv; ck = tk;
              }
            }
          }
        }
      }
    }
  }

  // Confidence: horizontal sums of q, then vertical sums (8-row mapping)
  __syncthreads();
  if (active1) {
    float s = 0.f;
#pragma unroll
    for (int t = 0; t < 21; ++t) s += qreg[t];
    float rs[8];
    rs[0] = s;
#pragma unroll
    for (int j = 1; j < 8; ++j) {
      s += qreg[j + 20] - qreg[j - 1];
      rs[j] = s;
    }
    float4* w = (float4*)&rsb0[prow_ * RSTR + c0];
    w[0] = make_float4(rs[0], rs[1], rs[2], rs[3]);
    w[1] = make_float4(rs[4], rs[5], rs[6], rs[7]);
  }
  __syncthreads();

  unsigned* cntN = wl;
  unsigned* cntD = wl + 1;
  uint4* entries = (uint4*)(wl + 8);
  const unsigned capHalf = capE >> 1;
  const int confoff = 4 * 2 * HH * WW;
  if (active2) {
    float s = 0.f;
#pragma unroll
    for (int u = 0; u < 21; ++u) s += rsb0[(r0 + u) * RSTR + col];
#pragma unroll
    for (int j = 0; j < 8; ++j) {
      if (j > 0) s += rsb0[(r0 + 20 + j) * RSTR + col]
                    - rsb0[(r0 + j - 1) * RSTR + col];
      int y = y0 + r0 + j;
      int x = x0 + col;
      int ny = min(y + 10, HH - 1) - max(y - 10, 0) + 1;
      int nx = min(x + 10, WW - 1) - max(x - 10, 0) + 1;
      float c = (s + (float)(ny * nx)) * (1.f / 882.f);
      float conf = fminf(fmaxf(c, 0.f), 1.f);

      int kwin = bk[j][0];
      float ofx = (float)(kwin % 19 - 9);
      float ofy = (float)(kwin / 19 - 9);

      if (bv[j][0] - bv[j][1] <= MARGIN) {
        int cand[4];
        int n = 1; cand[0] = bk[j][0];
#pragma unroll
        for (int t = 1; t < 4; ++t)
          if (bv[j][0] - bv[j][t] <= MARGIN) cand[n++] = bk[j][t];
        bool deep = (bv[j][0] - bv[j][3] <= MARGIN);
        unsigned pix = (unsigned)((b * HH + y) * WW + x);
        bool stored = false;
        if (!deep) {
          unsigned slot = atomicAdd(cntN, 1u);
          if (slot < capHalf) {
            unsigned kk[4];
#pragma unroll
            for (int t = 0; t < 4; ++t)
              kk[t] = (t < n) ? (unsigned)cand[t] : 0xFFFFu;
            uint4 e;
            e.x = pix;
            e.y = kk[0] | (kk[1] << 16);
            e.z = kk[2] | (kk[3] << 16);
            e.w = 0u;
            entries[slot] = e;
            stored = true;
          }
        } else {
          unsigned ds = atomicAdd(cntD, 1u);
          if (ds < capHalf) {
            uint4 e; e.x = pix; e.y = 0u; e.z = 0u; e.w = 0u;
            entries[capE - 1 - ds] = e;
            stored = true;
          }
        }
        if (!stored) {
          int c2 = (n > 2) ? cand[2] : cand[0];
          int c3 = (n > 3) ? cand[3] : cand[0];
          int dpf = deep ? 1 : 0;
          ofx = (float)(1000000 + cand[0] + 512 * cand[1]);
          ofy = (float)(c2 + 512 * c3 + 262144 * dpf);
        }
      }
      out[((b * 2 + 0) * HH + y) * WW + x] = ofx;
      out[((b * 2 + 1) * HH + y) * WW + x] = ofy;
      out[confoff + (b * HH + y) * WW + x] = conf;
    }
  }
}

// Normal entries: 16 per wave (lane quad per entry, shfl_xor reduce).
// Deep entries: one wave per entry, 361 offsets split across lanes.
// Then (only if the worklist overflowed) a grid-stride sentinel scan.
__global__ __launch_bounds__(256)
void bcm_pass2(const float* __restrict__ p1, const float* __restrict__ p2,
               float* __restrict__ out, const unsigned* __restrict__ wl,
               unsigned capE) {
  const unsigned capHalf = capE >> 1;
  unsigned rawN = wl[0], rawD = wl[1];
  unsigned nN = rawN > capHalf ? capHalf : rawN;
  unsigned nD = rawD > capHalf ? capHalf : rawD;
  const uint4* entries = (const uint4*)(wl + 8);
  const int lane = threadIdx.x & 63;
  unsigned wid = blockIdx.x * (blockDim.x >> 6) + (threadIdx.x >> 6);
  unsigned nw = gridDim.x * (blockDim.x >> 6);

  // normal entries
  for (unsigned base = wid * 16; base < nN; base += nw * 16) {
    unsigned e = base + (lane >> 2);
    int c = lane & 3;
    float wv = -1e30f;
    int   wk = 0x7FFF;
    unsigned pix = 0;
    bool valid = (e < nN);
    if (valid) {
      uint4 ent = entries[e];
      pix = ent.x;
      unsigned kc = (c == 0) ? (ent.y & 0xFFFFu) :
                    (c == 1) ? (ent.y >> 16) :
                    (c == 2) ? (ent.z & 0xFFFFu) : (ent.z >> 16);
      if (kc != 0xFFFFu) {
        int b = pix / (HH * WW);
        int r = pix - b * (HH * WW);
        int y = r / WW, x = r - y * WW;
        wv = replay_corr(p1 + b * HH * WW, p2 + b * HH * WW, y, x, (int)kc);
        wk = (int)kc;
      }
    }
#pragma unroll
    for (int d = 1; d <= 2; d <<= 1) {
      float ov = __shfl_xor(wv, d, 64);
      int   ok = __shfl_xor(wk, d, 64);
      if (ov > wv || (ov == wv && ok < wk)) { wv = ov; wk = ok; }
    }
    if (valid && c == 0) {
      int b = pix / (HH * WW);
      int r = pix - b * (HH * WW);
      int y = r / WW, x = r - y * WW;
      int fxi = (b * 2 * HH + y) * WW + x;
      out[fxi] = (float)(wk % 19 - 9);
      out[fxi + HH * WW] = (float)(wk / 19 - 9);
    }
  }

  // deep entries
  for (unsigned d = wid; d < nD; d += nw) {
    uint4 ent = entries[capE - 1 - d];
    unsigned pix = ent.x;
    int b = pix / (HH * WW);
    int r = pix - b * (HH * WW);
    int y = r / WW, x = r - y * WW;
    const float* p1b = p1 + b * HH * WW;
    const float* p2b = p2 + b * HH * WW;
    float wv = -1e30f;
    int   wk = 0x7FFF;
    for (int k = lane; k < 361; k += 64) {
      float s = replay_corr(p1b, p2b, y, x, k);
      if (s > wv || (s == wv && k < wk)) { wv = s; wk = k; }
    }
    for (int off = 32; off > 0; off >>= 1) {
      float ov = __shfl_down(wv, off, 64);
      int   ok = __shfl_down(wk, off, 64);
      if (ov > wv || (ov == wv && ok < wk)) { wv = ov; wk = ok; }
    }
    if (lane == 0) {
      int fxi = (b * 2 * HH + y) * WW + x;
      out[fxi] = (float)(wk % 19 - 9);
      out[fxi + HH * WW] = (float)(wk / 19 - 9);
    }
  }

  // sentinel cleanup — only if the worklist overflowed (normally skipped)
  if (rawN > capHalf || rawD > capHalf) {
    int stride = gridDim.x * blockDim.x;
    for (int idx = blockIdx.x * blockDim.x + threadIdx.x; idx < NPIX;
         idx += stride) {
      int b = idx / (HH * WW);
      int r = idx - b * (HH * WW);
      int fxi = b * 2 * HH * WW + r;
      float fx = out[fxi];
      if (fx < 500000.f) continue;  // not a sentinel
      int fyi = fxi + HH * WW;
      int p = (int)fx - 1000000;
      int q = (int)out[fyi];
      int deep = q >> 18;
      int kk[4] = {p & 511, p >> 9, q & 511, (q >> 9) & 511};
      int y = r / WW, x = r - y * WW;
      const float* p1b = p1 + b * HH * WW;
      const float* p2b = p2 + b * HH * WW;
      float wv = 0.f; int win = -1;
      if (deep) {
        for (int k = 0; k < 361; ++k) {
          float s = replay_corr(p1b, p2b, y, x, k);
          if (win < 0 || s > wv) { wv = s; win = k; }
        }
      } else {
        for (int c = 0; c < 4; ++c) {
          int k = kk[c];
          float s = replay_corr(p1b, p2b, y, x, k);
          if (win < 0 || s > wv || (s == wv && k < win)) { wv = s; win = k; }
        }
      }
      out[fxi] = (float)(win % 19 - 9);
      out[fyi] = (float)(win / 19 - 9);
    }
  }
}

extern "C" void kernel_launch(void* const* d_in, const int* in_sizes, int n_in,
                              void* d_out, int out_size, void* d_ws, size_t ws_size,
                              hipStream_t stream) {
  const float* p1 = (const float*)d_in[0];
  const float* p2 = (const float*)d_in[1];
  float* out = (float*)d_out;
  unsigned* wl = (unsigned*)d_ws;
  unsigned capE = (ws_size >= 64) ? (unsigned)((ws_size - 32) / 16) : 0u;
  hipMemsetAsync(d_ws, 0, 32, stream);  // worklist counters
  dim3 grid1(WW / TW, HH / TH, 4);
  bcm_pass1<<<grid1, dim3(256), 0, stream>>>(p1, p2, out, wl, capE);
  bcm_pass2<<<dim3(512), dim3(256), 0, stream>>>(p1, p2, out, wl, capE);
}

// Round 21
// 719.622 us; speedup vs baseline: 2.0666x; 2.0666x over previous
//
#include <hip/hip_runtime.h>

// BinaryCorrelationMatcher: B=4, H=480, W=640, TEMPLATE=21 (pad 10), SEARCH=9.
//
// VERIFIED reference model (R14): corr = flat forward-raster sequential f32
// sum over 441 taps of the FMA-contracted agreement:
//   agr = fma(p1, s2, fl( fl(1-p1) * fl(1-s2) ));  s = fl(s + agr)
// s2 = shifted p2 (0 outside image); OOB taps exact +0 no-ops.
// Winner = (max f32, min k) = lax.scan strict-> first-wins.
//
// R21 = VERBATIM REVERT to the R18 optimum (720 us). R19 (tree-sum register
// arrays) and R20 (8-row phase2, bv/bk[8][4]) both blew the 128-VGPR cap of
// launch_bounds(256,4) and spilled to scratch (WRITE_SIZE 14.6->23->43.5 MB,
// VALUBusy 61->22%). R18 sits at the register-budget boundary: any added
// per-thread state spills. Structure: q-taps global->28 regs (no qs LDS
// tile); p-taps in a CIRCULAR 28-reg window (dx loop fully unrolled, 1 LDS
// refill per dx); rowsum slabs PING-PONGED -> ONE barrier per offset
// (iter k writes slab k&1, barrier, reads slab k&1; program order makes the
// read-drain barrier redundant). LDS 34.9K -> 4 blocks/CU.
// MARGIN 0.002 (R17): pass1-vs-ref sigma ~1.4e-4; budget 1e-3 = ~7 sigma.
// Flagged: normal -> front worklist (<=4 cands); deep -> back worklist
// (361-replay). Overflow -> sentinel in flow slots.
//
// Pass 2: normal entries 16/wave (lane quad, shfl_xor reduce); deep
// wave-per-entry; then overflow-gated sentinel scan (normally skipped).
//
// Confidence: clip(((boxsum(q)+Nvalid)/2)/441, 0, 1), f32 (threshold 0.02).

#define HH 480
#define WW 640
#define TH 32
#define TW 32
#define QROWS 52   // TH+20
#define PROWS 70   // TH+38
#define PCOLS 70   // TW+38
#define PSTR  71
#define RSTR  36   // f32 rowsum slab stride (mult of 4 -> float4 writes)
#define MARGIN 0.002f
#define NPIX (4 * HH * WW)

// Bit-exact replica: forward-raster sequential f32 sum of FMA-contracted taps.
__device__ __forceinline__ float replay_corr(const float* __restrict__ p1b,
                                             const float* __restrict__ p2b,
                                             int y, int x, int k) {
  int dy = k / 19 - 9, dx = k % 19 - 9;
  float s = 0.f;
  for (int u = 0; u < 21; ++u) {
    int yy = y - 10 + u;
    if (yy < 0 || yy >= HH) continue;  // +0 taps: exact no-ops
    int y2 = yy + dy;
    bool yok = (y2 >= 0 && y2 < HH);
    const float* r1 = p1b + yy * WW;
    const float* r2 = p2b + y2 * WW;
#pragma unroll
    for (int v = 0; v < 21; ++v) {
      int xx = x - 10 + v;
      if (xx < 0 || xx >= WW) continue;  // +0 tap: exact no-op
      float p = r1[xx];
      int x2 = xx + dx;
      float s2 = (yok && x2 >= 0 && x2 < WW) ? r2[x2] : 0.f;
      float t2 = __fmul_rn(__fsub_rn(1.f, p), __fsub_rn(1.f, s2));
      float agr = __fmaf_rn(p, s2, t2);
      s = __fadd_rn(s, agr);
    }
  }
  return s;
}

__global__ __launch_bounds__(256, 4)
void bcm_pass1(const float* __restrict__ p1, const float* __restrict__ p2,
               float* __restrict__ out, unsigned* __restrict__ wl,
               unsigned capE) {
  __shared__ float ps[PROWS * PSTR];
  __shared__ __align__(16) float rsb0[QROWS * RSTR];
  __shared__ __align__(16) float rsb1[QROWS * RSTR];

  const int tid = threadIdx.x;
  const int b  = blockIdx.z;
  const int y0 = blockIdx.y * TH;
  const int x0 = blockIdx.x * TW;
  const float* p1b = p1 + b * HH * WW;
  const float* p2b = p2 + b * HH * WW;

  // stage p2 tile (halo 19) into LDS
  for (int i = tid; i < PROWS * PCOLS; i += 256) {
    int rr = i / PCOLS, cc = i - rr * PCOLS;
    int Y = y0 - 19 + rr, X = x0 - 19 + cc;
    float v = 0.f;
    if (Y >= 0 && Y < HH && X >= 0 && X < WW) v = p2b[Y * WW + X];
    ps[rr * PSTR + cc] = v;
  }

  const int col = tid & 31;
  const int r0  = (tid >> 5) * 4;
  const int prow_ = tid >> 2;
  const int c0    = (tid & 3) * 8;
  const bool active1 = (prow_ < QROWS);

  // q taps straight from global into registers (28 = 21 + 7 for 8 cols)
  float qreg[28];
  if (active1) {
    int Y = y0 - 10 + prow_;
    bool yok = (Y >= 0 && Y < HH);
    const float* qrow = p1b + Y * WW;
#pragma unroll
    for (int t = 0; t < 28; ++t) {
      int X = x0 - 10 + c0 + t;
      float v = 0.f;
      if (yok && X >= 0 && X < WW) v = 2.f * qrow[X] - 1.f;
      qreg[t] = v;
    }
  }
  __syncthreads();

  // top-4 candidates per output pixel (sorted descending)
  float bv[4][4];
  int   bk[4][4];
#pragma unroll
  for (int j = 0; j < 4; ++j)
#pragma unroll
    for (int t = 0; t < 4; ++t) { bv[j][t] = -1e30f; bk[j][t] = 0; }

  float preg[28];  // circular window of p taps
  int k = 0;
  for (int dy = -9; dy <= 9; ++dy) {
    const float* prowp = active1 ? &ps[(prow_ + dy + 9) * PSTR + c0] : ps;
    if (active1) {
#pragma unroll
      for (int t = 0; t < 28; ++t) preg[t] = prowp[t];
    }
#pragma unroll
    for (int dxi = 0; dxi < 19; ++dxi, ++k) {
      float* slab = (k & 1) ? rsb1 : rsb0;
      if (active1) {
        float s = 0.f;
#pragma unroll
        for (int t = 0; t < 21; ++t) s += qreg[t] * preg[(dxi + t) % 28];
        float rs[8];
        rs[0] = s;
#pragma unroll
        for (int j = 1; j < 8; ++j) {
          s += qreg[j + 20] * preg[(dxi + j + 20) % 28]
             - qreg[j - 1] * preg[(dxi + j - 1) % 28];
          rs[j] = s;
        }
        float4* w = (float4*)&slab[prow_ * RSTR + c0];
        w[0] = make_float4(rs[0], rs[1], rs[2], rs[3]);
        w[1] = make_float4(rs[4], rs[5], rs[6], rs[7]);
        if (dxi < 18) preg[dxi % 28] = prowp[dxi + 28];  // next tap into freed slot
      }
      __syncthreads();  // single barrier per offset (ping-pong slabs)
      {
        float s = 0.f;
#pragma unroll
        for (int u = 0; u < 21; ++u) s += slab[(r0 + u) * RSTR + col];
#pragma unroll
        for (int j = 0; j < 4; ++j) {
          if (j > 0) s += slab[(r0 + 20 + j) * RSTR + col]
                        - slab[(r0 + j - 1) * RSTR + col];
          float cv = s;
          if (cv > bv[j][3]) {
            int ck = k;
#pragma unroll
            for (int t = 0; t < 4; ++t) {   // sorted-insert; strict >
              if (cv > bv[j][t]) {
                float tv = bv[j][t]; int tk = bk[j][t];
                bv[j][t] = cv; bk[j][t] = ck;
                cv = tv; ck = tk;
              }
            }
          }
        }
      }
    }
  }

  // Confidence: horizontal sums of q (reuse qreg), then vertical sums
  __syncthreads();  // drain last slab read before reuse
  if (active1) {
    float s = 0.f;
#pragma unroll
    for (int t = 0; t < 21; ++t) s += qreg[t];
    float rs[8];
    rs[0] = s;
#pragma unroll
    for (int j = 1; j < 8; ++j) {
      s += qreg[j + 20] - qreg[j - 1];
      rs[j] = s;
    }
    float4* w = (float4*)&rsb0[prow_ * RSTR + c0];
    w[0] = make_float4(rs[0], rs[1], rs[2], rs[3]);
    w[1] = make_float4(rs[4], rs[5], rs[6], rs[7]);
  }
  __syncthreads();

  unsigned* cntN = wl;
  unsigned* cntD = wl + 1;
  uint4* entries = (uint4*)(wl + 8);
  const unsigned capHalf = capE >> 1;
  const int confoff = 4 * 2 * HH * WW;
  {
    float s = 0.f;
#pragma unroll
    for (int u = 0; u < 21; ++u) s += rsb0[(r0 + u) * RSTR + col];
#pragma unroll
    for (int j = 0; j < 4; ++j) {
      if (j > 0) s += rsb0[(r0 + 20 + j) * RSTR + col]
                    - rsb0[(r0 + j - 1) * RSTR + col];
      int y = y0 + r0 + j;
      int x = x0 + col;
      int ny = min(y + 10, HH - 1) - max(y - 10, 0) + 1;
      int nx = min(x + 10, WW - 1) - max(x - 10, 0) + 1;
      float c = (s + (float)(ny * nx)) * (1.f / 882.f);
      float conf = fminf(fmaxf(c, 0.f), 1.f);

      int kwin = bk[j][0];
      float ofx = (float)(kwin % 19 - 9);
      float ofy = (float)(kwin / 19 - 9);

      if (bv[j][0] - bv[j][1] <= MARGIN) {
        int cand[4];
        int n = 1; cand[0] = bk[j][0];
#pragma unroll
        for (int t = 1; t < 4; ++t)
          if (bv[j][0] - bv[j][t] <= MARGIN) cand[n++] = bk[j][t];
        bool deep = (bv[j][0] - bv[j][3] <= MARGIN);
        unsigned pix = (unsigned)((b * HH + y) * WW + x);
        bool stored = false;
        if (!deep) {
          unsigned slot = atomicAdd(cntN, 1u);
          if (slot < capHalf) {
            unsigned kk[4];
#pragma unroll
            for (int t = 0; t < 4; ++t)
              kk[t] = (t < n) ? (unsigned)cand[t] : 0xFFFFu;
            uint4 e;
            e.x = pix;
            e.y = kk[0] | (kk[1] << 16);
            e.z = kk[2] | (kk[3] << 16);
            e.w = 0u;
            entries[slot] = e;
            stored = true;
          }
        } else {
          unsigned ds = atomicAdd(cntD, 1u);
          if (ds < capHalf) {
            uint4 e; e.x = pix; e.y = 0u; e.z = 0u; e.w = 0u;
            entries[capE - 1 - ds] = e;
            stored = true;
          }
        }
        if (!stored) {
          // overflow fallback: sentinel-encode candidates into flow slots
          int c2 = (n > 2) ? cand[2] : cand[0];
          int c3 = (n > 3) ? cand[3] : cand[0];
          int dpf = deep ? 1 : 0;
          ofx = (float)(1000000 + cand[0] + 512 * cand[1]);
          ofy = (float)(c2 + 512 * c3 + 262144 * dpf);
        }
      }
      out[((b * 2 + 0) * HH + y) * WW + x] = ofx;
      out[((b * 2 + 1) * HH + y) * WW + x] = ofy;
      out[confoff + (b * HH + y) * WW + x] = conf;
    }
  }
}

// Normal entries: 16 per wave (lane quad per entry, shfl_xor reduce).
// Deep entries: one wave per entry, 361 offsets split across lanes.
// Then (only if the worklist overflowed) a grid-stride sentinel scan.
__global__ __launch_bounds__(256)
void bcm_pass2(const float* __restrict__ p1, const float* __restrict__ p2,
               float* __restrict__ out, const unsigned* __restrict__ wl,
               unsigned capE) {
  const unsigned capHalf = capE >> 1;
  unsigned rawN = wl[0], rawD = wl[1];
  unsigned nN = rawN > capHalf ? capHalf : rawN;
  unsigned nD = rawD > capHalf ? capHalf : rawD;
  const uint4* entries = (const uint4*)(wl + 8);
  const int lane = threadIdx.x & 63;
  unsigned wid = blockIdx.x * (blockDim.x >> 6) + (threadIdx.x >> 6);
  unsigned nw = gridDim.x * (blockDim.x >> 6);

  // normal entries
  for (unsigned base = wid * 16; base < nN; base += nw * 16) {
    unsigned e = base + (lane >> 2);
    int c = lane & 3;
    float wv = -1e30f;
    int   wk = 0x7FFF;
    unsigned pix = 0;
    bool valid = (e < nN);
    if (valid) {
      uint4 ent = entries[e];
      pix = ent.x;
      unsigned kc = (c == 0) ? (ent.y & 0xFFFFu) :
                    (c == 1) ? (ent.y >> 16) :
                    (c == 2) ? (ent.z & 0xFFFFu) : (ent.z >> 16);
      if (kc != 0xFFFFu) {
        int b = pix / (HH * WW);
        int r = pix - b * (HH * WW);
        int y = r / WW, x = r - y * WW;
        wv = replay_corr(p1 + b * HH * WW, p2 + b * HH * WW, y, x, (int)kc);
        wk = (int)kc;
      }
    }
#pragma unroll
    for (int d = 1; d <= 2; d <<= 1) {
      float ov = __shfl_xor(wv, d, 64);
      int   ok = __shfl_xor(wk, d, 64);
      if (ov > wv || (ov == wv && ok < wk)) { wv = ov; wk = ok; }
    }
    if (valid && c == 0) {
      int b = pix / (HH * WW);
      int r = pix - b * (HH * WW);
      int y = r / WW, x = r - y * WW;
      int fxi = (b * 2 * HH + y) * WW + x;
      out[fxi] = (float)(wk % 19 - 9);
      out[fxi + HH * WW] = (float)(wk / 19 - 9);
    }
  }

  // deep entries
  for (unsigned d = wid; d < nD; d += nw) {
    uint4 ent = entries[capE - 1 - d];
    unsigned pix = ent.x;
    int b = pix / (HH * WW);
    int r = pix - b * (HH * WW);
    int y = r / WW, x = r - y * WW;
    const float* p1b = p1 + b * HH * WW;
    const float* p2b = p2 + b * HH * WW;
    float wv = -1e30f;
    int   wk = 0x7FFF;
    for (int k = lane; k < 361; k += 64) {
      float s = replay_corr(p1b, p2b, y, x, k);
      if (s > wv || (s == wv && k < wk)) { wv = s; wk = k; }
    }
    for (int off = 32; off > 0; off >>= 1) {
      float ov = __shfl_down(wv, off, 64);
      int   ok = __shfl_down(wk, off, 64);
      if (ov > wv || (ov == wv && ok < wk)) { wv = ov; wk = ok; }
    }
    if (lane == 0) {
      int fxi = (b * 2 * HH + y) * WW + x;
      out[fxi] = (float)(wk % 19 - 9);
      out[fxi + HH * WW] = (float)(wk / 19 - 9);
    }
  }

  // sentinel cleanup — only if the worklist overflowed (normally skipped)
  if (rawN > capHalf || rawD > capHalf) {
    int stride = gridDim.x * blockDim.x;
    for (int idx = blockIdx.x * blockDim.x + threadIdx.x; idx < NPIX;
         idx += stride) {
      int b = idx / (HH * WW);
      int r = idx - b * (HH * WW);
      int fxi = b * 2 * HH * WW + r;
      float fx = out[fxi];
      if (fx < 500000.f) continue;  // not a sentinel
      int fyi = fxi + HH * WW;
      int p = (int)fx - 1000000;
      int q = (int)out[fyi];
      int deep = q >> 18;
      int kk[4] = {p & 511, p >> 9, q & 511, (q >> 9) & 511};
      int y = r / WW, x = r - y * WW;
      const float* p1b = p1 + b * HH * WW;
      const float* p2b = p2 + b * HH * WW;
      float wv = 0.f; int win = -1;
      if (deep) {
        for (int k = 0; k < 361; ++k) {
          float s = replay_corr(p1b, p2b, y, x, k);
          if (win < 0 || s > wv) { wv = s; win = k; }
        }
      } else {
        for (int c = 0; c < 4; ++c) {
          int k = kk[c];
          float s = replay_corr(p1b, p2b, y, x, k);
          if (win < 0 || s > wv || (s == wv && k < win)) { wv = s; win = k; }
        }
      }
      out[fxi] = (float)(win % 19 - 9);
      out[fyi] = (float)(win / 19 - 9);
    }
  }
}

extern "C" void kernel_launch(void* const* d_in, const int* in_sizes, int n_in,
                              void* d_out, int out_size, void* d_ws, size_t ws_size,
                              hipStream_t stream) {
  const float* p1 = (const float*)d_in[0];
  const float* p2 = (const float*)d_in[1];
  float* out = (float*)d_out;
  unsigned* wl = (unsigned*)d_ws;
  unsigned capE = (ws_size >= 64) ? (unsigned)((ws_size - 32) / 16) : 0u;
  hipMemsetAsync(d_ws, 0, 32, stream);  // worklist counters
  dim3 grid1(WW / TW, HH / TH, 4);
  bcm_pass1<<<grid1, dim3(256), 0, stream>>>(p1, p2, out, wl, capE);
  bcm_pass2<<<dim3(512), dim3(256), 0, stream>>>(p1, p2, out, wl, capE);
}